// Round 2
// baseline (625.501 us; speedup 1.0000x reference)
//
#include <hip/hip_runtime.h>
#include <math.h>

#define IMSZ 28
#define PSZ  8
#define LAMF 0.001f
#define NREP 16          // coact atomic replica buffers
#define CSTRIDE 240      // floats per replica (225 used, padded)
#define SSTR 17          // sS row stride (bank-conflict-free)

// One persistent kernel, plain launch: all 5 steps fused.
// grid = 256 blocks (1 per CU, co-residency by construction: <=128 VGPR via
// launch_bounds, 26KB LDS, 16 waves). 1024 threads = 128 groups of 8 lanes;
// each group owns 2 samples -> 256 samples/block. State lives in LDS,
// positions in registers. Cross-block per step: 15x15 coact partials via
// 16-replica atomicAdd, then a counter barrier (release-fence / acquire-spin).
__global__ __launch_bounds__(1024, 4) void fused5(
    const float* __restrict__ x,
    const float* __restrict__ Wi, const float* __restrict__ bi,
    const float* __restrict__ gamma, const float* __restrict__ beta,
    const float* __restrict__ R, const float* __restrict__ rb,
    const float* __restrict__ mask,
    const float* __restrict__ Wc, const float* __restrict__ bc,
    const float* __restrict__ Wo, const float* __restrict__ bo,
    float* __restrict__ coact, unsigned* __restrict__ bar,
    float* __restrict__ out, float invB, int nblk)
{
    __shared__ float sWi[15 * 72];          // row stride 72
    __shared__ float sBi[16], sGa[16], sBe[16], sRb[16];
    __shared__ float sWc[32], sBc[2], sWo[160], sBo[16];
    __shared__ float sRm[226], sLm[226];    // R*mask, (LAM/B)*mask
    __shared__ float sReff[240];            // 225 live + zero pad (c==7 column)
    __shared__ float sS[256 * SSTR];        // per-block state [sample][unit]

    const int tid = threadIdx.x;

    // ---- stage constants ONCE (disjoint thread ranges) ----
    for (int idx = tid; idx < 990; idx += 1024) {
        int u = idx / 66, k = idx - u * 66;
        sWi[u * 72 + k] = Wi[idx];
    }
    if (tid < 15) {
        sBi[tid] = bi[tid]; sGa[tid] = gamma[tid];
        sBe[tid] = beta[tid]; sRb[tid] = rb[tid];
    }
    if (tid >= 32 && tid < 62)  sWc[tid - 32] = Wc[tid - 32];
    if (tid >= 62 && tid < 64)  sBc[tid - 62] = bc[tid - 62];
    if (tid >= 96 && tid < 246) sWo[tid - 96] = Wo[tid - 96];
    if (tid >= 246 && tid < 256) sBo[tid - 246] = bo[tid - 246];
    if (tid >= 256 && tid < 481) {
        int t = tid - 256;
        float m = mask[t];
        sRm[t] = R[t] * m;
        sLm[t] = (LAMF * invB) * m;
    }
    if (tid >= 481 && tid < 496) sReff[tid - 256] = 0.0f;   // pad stays 0
    __syncthreads();

    const int g = tid >> 3;                  // group / sample slot (0..127)
    const int c = tid & 7;                   // lane handles patch COLUMN c
    const int b0 = blockIdx.x * 256 + g;
    const int b1 = b0 + 128;
    const float* img0 = x + (size_t)b0 * (IMSZ * IMSZ);
    const float* img1 = x + (size_t)b1 * (IMSZ * IMSZ);

    int pr0 = 10, pc0 = 10, pr1 = 10, pc1 = 10;
    float hA[15], hB[15];

    for (int s = 0; s < 5; ++s) {
        float sj0A = 0.f, sj1A = 0.f, sj0B = 0.f, sj1B = 0.f;
        if (s > 0) {
            // previous state: this lane's two recurrent columns (same slots
            // this lane will later overwrite -- no cross-thread hazard)
            sj0A = sS[g * SSTR + c];
            sj0B = sS[(g + 128) * SSTR + c];
            if (c < 7) {
                sj1A = sS[g * SSTR + 8 + c];
                sj1B = sS[(g + 128) * SSTR + 8 + c];
            }
            // build Reff from last step's replica sums (agent-scope loads:
            // coherent point; ordered by the barrier's acquire)
            if (tid < 225) {
                const float* ci = coact + (size_t)(s - 1) * (NREP * CSTRIDE) + tid;
                float cv = 0.0f;
#pragma unroll
                for (int r = 0; r < NREP; ++r)
                    cv += __hip_atomic_load(ci + (size_t)r * CSTRIDE,
                                            __ATOMIC_RELAXED, __HIP_MEMORY_SCOPE_AGENT);
                sReff[tid] = sRm[tid] - sLm[tid] * cv;
            }
            __syncthreads();                 // sReff ready
        }

        // ---- patch gather, lane=col: per instruction each group reads a
        // 32B contiguous run (8-16 lines/wave vs 64 with lane=row) ----
        float pA[8], pB[8];
        {
            const float* q0 = img0 + pr0 * IMSZ + pc0 + c;
            const float* q1 = img1 + pr1 * IMSZ + pc1 + c;
#pragma unroll
            for (int r = 0; r < 8; ++r) { pA[r] = q0[r * IMSZ]; pB[r] = q1[r * IMSZ]; }
        }

        const float fr0 = ((float)pr0 / 20.0f) * 2.0f - 1.0f;
        const float fc0 = ((float)pc0 / 20.0f) * 2.0f - 1.0f;
        const float fr1 = ((float)pr1 / 20.0f) * 2.0f - 1.0f;
        const float fc1 = ((float)pc1 / 20.0f) * 2.0f - 1.0f;

        // ---- k-partial matvec, both samples share each weight read ----
#pragma unroll
        for (int u = 0; u < 15; ++u) {
            float a = 0.f, bq = 0.f;
            const float* w = sWi + u * 72 + c;
#pragma unroll
            for (int r = 0; r < 8; ++r) {
                float wv = w[r * 8];         // W[u][r*8+c]
                a  = fmaf(pA[r], wv, a);
                bq = fmaf(pB[r], wv, bq);
            }
            if (s > 0) {
                float w0 = sReff[u * 15 + c];
                float w1 = sReff[u * 15 + 8 + c];   // c==7 hits zero pad, sj1==0
                a  = fmaf(sj0A, w0, a);  a  = fmaf(sj1A, w1, a);
                bq = fmaf(sj0B, w0, bq); bq = fmaf(sj1B, w1, bq);
            }
            if (c == 0) {
                float wr = sWi[u * 72 + 64], wc = sWi[u * 72 + 65];
                float bias = sBi[u] + ((s > 0) ? sRb[u] : 0.0f);
                a  = fmaf(fr0, wr, a);  a  = fmaf(fc0, wc, a);  a  += bias;
                bq = fmaf(fr1, wr, bq); bq = fmaf(fc1, wc, bq); bq += bias;
            }
            hA[u] = a; hB[u] = bq;
        }

        // ---- 8-lane butterfly all-reduce (round-0-proven), relu ----
#pragma unroll
        for (int u = 0; u < 15; ++u) {
            float vA = hA[u], vB = hB[u];
            vA += __shfl_xor(vA, 1); vB += __shfl_xor(vB, 1);
            vA += __shfl_xor(vA, 2); vB += __shfl_xor(vB, 2);
            vA += __shfl_xor(vA, 4); vB += __shfl_xor(vB, 4);
            hA[u] = fmaxf(vA, 0.0f);
            hB[u] = fmaxf(vB, 0.0f);
        }

        // ---- LayerNorm, in place (redundant per lane) ----
        float muA = 0.f, muB = 0.f;
#pragma unroll
        for (int u = 0; u < 15; ++u) { muA += hA[u]; muB += hB[u]; }
        muA *= (1.0f / 15.0f); muB *= (1.0f / 15.0f);
        float vA = 0.f, vB = 0.f;
#pragma unroll
        for (int u = 0; u < 15; ++u) {
            float dA = hA[u] - muA; vA = fmaf(dA, dA, vA);
            float dB = hB[u] - muB; vB = fmaf(dB, dB, vB);
        }
        vA *= (1.0f / 15.0f); vB *= (1.0f / 15.0f);
        const float rsA = 1.0f / sqrtf(vA + 1e-5f);
        const float rsB = 1.0f / sqrtf(vB + 1e-5f);
#pragma unroll
        for (int u = 0; u < 15; ++u) {
            hA[u] = (hA[u] - muA) * rsA * sGa[u] + sBe[u];
            hB[u] = (hB[u] - muB) * rsB * sGa[u] + sBe[u];
        }

        if (s == 4) {
            // ---- logits only on the last step, then done ----
#pragma unroll
            for (int rep = 0; rep < 2; ++rep) {
                int o = rep * 8 + c;
                if (o < 10) {
                    float a0 = 0.f, a1 = 0.f;
#pragma unroll
                    for (int j = 0; j < 15; ++j) {
                        a0 = fmaf(hA[j], sWo[o * 15 + j], a0);
                        a1 = fmaf(hB[j], sWo[o * 15 + j], a1);
                    }
                    out[(size_t)b0 * 10 + o] = a0 + sBo[o];
                    out[(size_t)b1 * 10 + o] = a1 + sBo[o];
                }
            }
        } else {
            // ---- control head + position update (registers only) ----
            float c0A = 0.f, c1A = 0.f, c0B = 0.f, c1B = 0.f;
#pragma unroll
            for (int j = 0; j < 15; ++j) {
                c0A = fmaf(hA[j], sWc[j],      c0A);
                c1A = fmaf(hA[j], sWc[15 + j], c1A);
                c0B = fmaf(hB[j], sWc[j],      c0B);
                c1B = fmaf(hB[j], sWc[15 + j], c1B);
            }
            c0A = tanhf(c0A + sBc[0]); c1A = tanhf(c1A + sBc[1]);
            c0B = tanhf(c0B + sBc[0]); c1B = tanhf(c1B + sBc[1]);
            {
                float m0 = fabsf(c0A), m1 = fabsf(c1A);
                int rm, cm;
                if (m0 >= m1) { rm = (c0A > 0.f) - (c0A < 0.f); cm = 0; }
                else          { rm = 0; cm = (c1A > 0.f) - (c1A < 0.f); }
                pr0 = min(max(pr0 + rm, 0), IMSZ - PSZ);
                pc0 = min(max(pc0 + cm, 0), IMSZ - PSZ);
            }
            {
                float m0 = fabsf(c0B), m1 = fabsf(c1B);
                int rm, cm;
                if (m0 >= m1) { rm = (c0B > 0.f) - (c0B < 0.f); cm = 0; }
                else          { rm = 0; cm = (c1B > 0.f) - (c1B < 0.f); }
                pr1 = min(max(pr1 + rm, 0), IMSZ - PSZ);
                pc1 = min(max(pc1 + cm, 0), IMSZ - PSZ);
            }

            // ---- publish new state to LDS (compile-time reg indices only) ----
#pragma unroll
            for (int k = 0; k < 8; ++k) {
                if (c == k) {
                    sS[g * SSTR + k]         = hA[k];
                    sS[(g + 128) * SSTR + k] = hB[k];
                    if (k < 7) {
                        sS[g * SSTR + 8 + k]         = hA[8 + k];
                        sS[(g + 128) * SSTR + 8 + k] = hB[8 + k];
                    }
                }
            }
            __syncthreads();

            // ---- coact partials: 4 quarter-sets of 225 threads, 64 samples
            // each, 4 accumulators to break the fmaf dependency chain ----
            {
                const int q = tid >> 8;          // 0..3
                const int t = tid & 255;
                if (t < 225) {
                    int i = t / 15, j = t - i * 15;
                    const int base = q * 64;
                    float a0 = 0.f, a1 = 0.f, a2 = 0.f, a3 = 0.f;
#pragma unroll
                    for (int bb = 0; bb < 64; bb += 4) {
                        a0 = fmaf(sS[(base + bb + 0) * SSTR + i], sS[(base + bb + 0) * SSTR + j], a0);
                        a1 = fmaf(sS[(base + bb + 1) * SSTR + i], sS[(base + bb + 1) * SSTR + j], a1);
                        a2 = fmaf(sS[(base + bb + 2) * SSTR + i], sS[(base + bb + 2) * SSTR + j], a2);
                        a3 = fmaf(sS[(base + bb + 3) * SSTR + i], sS[(base + bb + 3) * SSTR + j], a3);
                    }
                    atomicAdd(&coact[(size_t)s * (NREP * CSTRIDE)
                                     + ((blockIdx.x * 4 + q) & (NREP - 1)) * CSTRIDE + t],
                              (a0 + a1) + (a2 + a3));
                }
            }

            // ---- device-wide barrier (one fresh counter per step) ----
            __threadfence();                  // release this block's atomics
            __syncthreads();
            if (tid == 0) {
                __hip_atomic_fetch_add(&bar[s * 16], 1u,
                                       __ATOMIC_ACQ_REL, __HIP_MEMORY_SCOPE_AGENT);
                while (__hip_atomic_load(&bar[s * 16],
                                         __ATOMIC_ACQUIRE, __HIP_MEMORY_SCOPE_AGENT)
                       < (unsigned)nblk)
                    __builtin_amdgcn_s_sleep(2);
            }
            __syncthreads();
        }
    }
}

extern "C" void kernel_launch(void* const* d_in, const int* in_sizes, int n_in,
                              void* d_out, int out_size, void* d_ws, size_t ws_size,
                              hipStream_t stream) {
    (void)n_in; (void)out_size; (void)ws_size;
    const float* x     = (const float*)d_in[0];
    const float* Wi    = (const float*)d_in[1];
    const float* bi    = (const float*)d_in[2];
    const float* gamma = (const float*)d_in[3];
    const float* beta  = (const float*)d_in[4];
    const float* R     = (const float*)d_in[5];
    const float* rb    = (const float*)d_in[6];
    const float* mask  = (const float*)d_in[7];
    const float* Wc    = (const float*)d_in[8];
    const float* bc    = (const float*)d_in[9];
    const float* Wo    = (const float*)d_in[10];
    const float* bo    = (const float*)d_in[11];
    float* out = (float*)d_out;

    const int B = in_sizes[0] / (IMSZ * IMSZ);
    const float invB = 1.0f / (float)B;
    int grid = B / 256;                      // 256 samples per block -> 256 blocks

    // workspace: coact 4 steps * NREP * CSTRIDE f32 | barrier counters (64B apart)
    float* coact = (float*)d_ws;
    unsigned* bar = (unsigned*)(coact + 4 * NREP * CSTRIDE);

    hipMemsetAsync(d_ws, 0,
                   (size_t)4 * NREP * CSTRIDE * sizeof(float) + 16 * 16 * sizeof(unsigned),
                   stream);

    fused5<<<grid, 1024, 0, stream>>>(
        x, Wi, bi, gamma, beta, R, rb, mask, Wc, bc, Wo, bo,
        coact, bar, out, invB, grid);
}

// Round 3
// 396.519 us; speedup vs baseline: 1.5775x; 1.5775x over previous
//
#include <hip/hip_runtime.h>
#include <math.h>

#define IMSZ 28
#define PSZ  8
#define LAMF 0.001f
#define CSTRIDE 240      // floats per coact slot (225 used, padded)
#define SSTR 17          // sS row stride (bank-conflict-free)
#define MAXBLK 256

// One persistent kernel, plain launch: all 5 steps fused.
// grid = 256 blocks x 1024 threads (16 waves, <=2 blocks/CU worst-case packing
// -> all 256 resident by capacity: deadlock-free). 128 groups of 8 lanes; each
// group owns 2 samples -> 256 samples/block. State lives in LDS, positions in
// registers.
//
// Cross-block sync per step (learned from round 2's 92%-idle disaster): NO
// atomic RMW, NO acquire/release, NO threadfence. Coact partials go to
// per-block private slots via RELAXED agent-scope stores (LLC-direct, no
// invalidate); completion is a per-block flag store; waiters poll flags with
// RELAXED agent loads (no L2 invalidate storm -> x stays cached across steps).
// Ordering is structural: __syncthreads() drains vmcnt, so slot stores are
// complete at the coherence point before the flag store issues.
__global__ __launch_bounds__(1024, 4) void fused5(
    const float* __restrict__ x,
    const float* __restrict__ Wi, const float* __restrict__ bi,
    const float* __restrict__ gamma, const float* __restrict__ beta,
    const float* __restrict__ R, const float* __restrict__ rb,
    const float* __restrict__ mask,
    const float* __restrict__ Wc, const float* __restrict__ bc,
    const float* __restrict__ Wo, const float* __restrict__ bo,
    float* __restrict__ coact, unsigned* __restrict__ bar,
    float* __restrict__ out, float invB, int nblk)
{
    __shared__ float sWi[15 * 72];          // row stride 72
    __shared__ float sBi[16], sGa[16], sBe[16], sRb[16];
    __shared__ float sWc[32], sBc[2], sWo[160], sBo[16];
    __shared__ float sRm[226], sLm[226];    // R*mask, (LAM/B)*mask
    __shared__ float sReff[240];            // 225 live + zero pad (c==7 column)
    __shared__ float sCoQ[4][226];          // quarter partials / quarter sums
    __shared__ float sS[256 * SSTR];        // per-block state [sample][unit]

    const int tid = threadIdx.x;

    // ---- stage constants ONCE (disjoint thread ranges) ----
    for (int idx = tid; idx < 990; idx += 1024) {
        int u = idx / 66, k = idx - u * 66;
        sWi[u * 72 + k] = Wi[idx];
    }
    if (tid < 15) {
        sBi[tid] = bi[tid]; sGa[tid] = gamma[tid];
        sBe[tid] = beta[tid]; sRb[tid] = rb[tid];
    }
    if (tid >= 32 && tid < 62)  sWc[tid - 32] = Wc[tid - 32];
    if (tid >= 62 && tid < 64)  sBc[tid - 62] = bc[tid - 62];
    if (tid >= 96 && tid < 246) sWo[tid - 96] = Wo[tid - 96];
    if (tid >= 246 && tid < 256) sBo[tid - 246] = bo[tid - 246];
    if (tid >= 256 && tid < 481) {
        int t = tid - 256;
        float m = mask[t];
        sRm[t] = R[t] * m;
        sLm[t] = (LAMF * invB) * m;
    }
    if (tid >= 481 && tid < 496) sReff[tid - 256] = 0.0f;   // pad stays 0
    __syncthreads();

    const int g = tid >> 3;                  // group / sample slot (0..127)
    const int c = tid & 7;                   // lane handles patch COLUMN c
    const int b0 = blockIdx.x * 256 + g;
    const int b1 = b0 + 128;
    const float* img0 = x + (size_t)b0 * (IMSZ * IMSZ);
    const float* img1 = x + (size_t)b1 * (IMSZ * IMSZ);

    int pr0 = 10, pc0 = 10, pr1 = 10, pc1 = 10;
    float hA[15], hB[15];

    for (int s = 0; s < 5; ++s) {
        float sj0A = 0.f, sj1A = 0.f, sj0B = 0.f, sj1B = 0.f;
        if (s > 0) {
            // previous state: this lane's two recurrent columns (stable since
            // last step's publish+sync; overwritten only after a later sync)
            sj0A = sS[g * SSTR + c];
            sj0B = sS[(g + 128) * SSTR + c];
            if (c < 7) {
                sj1A = sS[g * SSTR + 8 + c];
                sj1B = sS[(g + 128) * SSTR + 8 + c];
            }
            // ---- rebuild global coact: quarter q sums 64 block slots with
            // LLC-direct relaxed loads (no invalidate), 4 accumulators ----
            {
                const int q = tid >> 8;          // 0..3
                const int t = tid & 255;
                if (t < 225) {
                    const float* cb = coact
                        + ((size_t)(s - 1) * MAXBLK + q * 64) * CSTRIDE + t;
                    float a0 = 0.f, a1 = 0.f, a2 = 0.f, a3 = 0.f;
#pragma unroll 4
                    for (int k = 0; k < 64; k += 4) {
                        a0 += __hip_atomic_load(cb + (size_t)(k + 0) * CSTRIDE,
                                __ATOMIC_RELAXED, __HIP_MEMORY_SCOPE_AGENT);
                        a1 += __hip_atomic_load(cb + (size_t)(k + 1) * CSTRIDE,
                                __ATOMIC_RELAXED, __HIP_MEMORY_SCOPE_AGENT);
                        a2 += __hip_atomic_load(cb + (size_t)(k + 2) * CSTRIDE,
                                __ATOMIC_RELAXED, __HIP_MEMORY_SCOPE_AGENT);
                        a3 += __hip_atomic_load(cb + (size_t)(k + 3) * CSTRIDE,
                                __ATOMIC_RELAXED, __HIP_MEMORY_SCOPE_AGENT);
                    }
                    sCoQ[q][t] = (a0 + a1) + (a2 + a3);
                }
            }
            __syncthreads();
            if (tid < 225) {
                float cv = (sCoQ[0][tid] + sCoQ[1][tid])
                         + (sCoQ[2][tid] + sCoQ[3][tid]);
                sReff[tid] = sRm[tid] - sLm[tid] * cv;
            }
            __syncthreads();                 // sReff ready
        }

        // ---- patch gather, lane=col: per instruction each group reads a
        // 32B contiguous run ----
        float pA[8], pB[8];
        {
            const float* q0 = img0 + pr0 * IMSZ + pc0 + c;
            const float* q1 = img1 + pr1 * IMSZ + pc1 + c;
#pragma unroll
            for (int r = 0; r < 8; ++r) { pA[r] = q0[r * IMSZ]; pB[r] = q1[r * IMSZ]; }
        }

        const float fr0 = ((float)pr0 / 20.0f) * 2.0f - 1.0f;
        const float fc0 = ((float)pc0 / 20.0f) * 2.0f - 1.0f;
        const float fr1 = ((float)pr1 / 20.0f) * 2.0f - 1.0f;
        const float fc1 = ((float)pc1 / 20.0f) * 2.0f - 1.0f;

        // ---- k-partial matvec, both samples share each weight read ----
#pragma unroll
        for (int u = 0; u < 15; ++u) {
            float a = 0.f, bq = 0.f;
            const float* w = sWi + u * 72 + c;
#pragma unroll
            for (int r = 0; r < 8; ++r) {
                float wv = w[r * 8];         // W[u][r*8+c]
                a  = fmaf(pA[r], wv, a);
                bq = fmaf(pB[r], wv, bq);
            }
            if (s > 0) {
                float w0 = sReff[u * 15 + c];
                float w1 = sReff[u * 15 + 8 + c];   // c==7 hits zero pad, sj1==0
                a  = fmaf(sj0A, w0, a);  a  = fmaf(sj1A, w1, a);
                bq = fmaf(sj0B, w0, bq); bq = fmaf(sj1B, w1, bq);
            }
            if (c == 0) {
                float wr = sWi[u * 72 + 64], wc = sWi[u * 72 + 65];
                float bias = sBi[u] + ((s > 0) ? sRb[u] : 0.0f);
                a  = fmaf(fr0, wr, a);  a  = fmaf(fc0, wc, a);  a  += bias;
                bq = fmaf(fr1, wr, bq); bq = fmaf(fc1, wc, bq); bq += bias;
            }
            hA[u] = a; hB[u] = bq;
        }

        // ---- 8-lane butterfly all-reduce, relu ----
#pragma unroll
        for (int u = 0; u < 15; ++u) {
            float vA = hA[u], vB = hB[u];
            vA += __shfl_xor(vA, 1); vB += __shfl_xor(vB, 1);
            vA += __shfl_xor(vA, 2); vB += __shfl_xor(vB, 2);
            vA += __shfl_xor(vA, 4); vB += __shfl_xor(vB, 4);
            hA[u] = fmaxf(vA, 0.0f);
            hB[u] = fmaxf(vB, 0.0f);
        }

        // ---- LayerNorm, in place (redundant per lane) ----
        float muA = 0.f, muB = 0.f;
#pragma unroll
        for (int u = 0; u < 15; ++u) { muA += hA[u]; muB += hB[u]; }
        muA *= (1.0f / 15.0f); muB *= (1.0f / 15.0f);
        float vA = 0.f, vB = 0.f;
#pragma unroll
        for (int u = 0; u < 15; ++u) {
            float dA = hA[u] - muA; vA = fmaf(dA, dA, vA);
            float dB = hB[u] - muB; vB = fmaf(dB, dB, vB);
        }
        vA *= (1.0f / 15.0f); vB *= (1.0f / 15.0f);
        const float rsA = 1.0f / sqrtf(vA + 1e-5f);
        const float rsB = 1.0f / sqrtf(vB + 1e-5f);
#pragma unroll
        for (int u = 0; u < 15; ++u) {
            hA[u] = (hA[u] - muA) * rsA * sGa[u] + sBe[u];
            hB[u] = (hB[u] - muB) * rsB * sGa[u] + sBe[u];
        }

        if (s == 4) {
            // ---- logits only on the last step, then done ----
#pragma unroll
            for (int rep = 0; rep < 2; ++rep) {
                int o = rep * 8 + c;
                if (o < 10) {
                    float a0 = 0.f, a1 = 0.f;
#pragma unroll
                    for (int j = 0; j < 15; ++j) {
                        a0 = fmaf(hA[j], sWo[o * 15 + j], a0);
                        a1 = fmaf(hB[j], sWo[o * 15 + j], a1);
                    }
                    out[(size_t)b0 * 10 + o] = a0 + sBo[o];
                    out[(size_t)b1 * 10 + o] = a1 + sBo[o];
                }
            }
        } else {
            // ---- control head + position update (registers only) ----
            float c0A = 0.f, c1A = 0.f, c0B = 0.f, c1B = 0.f;
#pragma unroll
            for (int j = 0; j < 15; ++j) {
                c0A = fmaf(hA[j], sWc[j],      c0A);
                c1A = fmaf(hA[j], sWc[15 + j], c1A);
                c0B = fmaf(hB[j], sWc[j],      c0B);
                c1B = fmaf(hB[j], sWc[15 + j], c1B);
            }
            c0A = tanhf(c0A + sBc[0]); c1A = tanhf(c1A + sBc[1]);
            c0B = tanhf(c0B + sBc[0]); c1B = tanhf(c1B + sBc[1]);
            {
                float m0 = fabsf(c0A), m1 = fabsf(c1A);
                int rm, cm;
                if (m0 >= m1) { rm = (c0A > 0.f) - (c0A < 0.f); cm = 0; }
                else          { rm = 0; cm = (c1A > 0.f) - (c1A < 0.f); }
                pr0 = min(max(pr0 + rm, 0), IMSZ - PSZ);
                pc0 = min(max(pc0 + cm, 0), IMSZ - PSZ);
            }
            {
                float m0 = fabsf(c0B), m1 = fabsf(c1B);
                int rm, cm;
                if (m0 >= m1) { rm = (c0B > 0.f) - (c0B < 0.f); cm = 0; }
                else          { rm = 0; cm = (c1B > 0.f) - (c1B < 0.f); }
                pr1 = min(max(pr1 + rm, 0), IMSZ - PSZ);
                pc1 = min(max(pc1 + cm, 0), IMSZ - PSZ);
            }

            // ---- publish new state to LDS (compile-time reg indices only) ----
#pragma unroll
            for (int k = 0; k < 8; ++k) {
                if (c == k) {
                    sS[g * SSTR + k]         = hA[k];
                    sS[(g + 128) * SSTR + k] = hB[k];
                    if (k < 7) {
                        sS[g * SSTR + 8 + k]         = hA[8 + k];
                        sS[(g + 128) * SSTR + 8 + k] = hB[8 + k];
                    }
                }
            }
            __syncthreads();

            // ---- coact partials: 4 quarter-sets of 225 threads, 64 samples
            // each, 4 accumulators; combine in LDS (NO atomics) ----
            {
                const int q = tid >> 8;          // 0..3
                const int t = tid & 255;
                if (t < 225) {
                    int i = t / 15, j = t - i * 15;
                    const int base = q * 64;
                    float a0 = 0.f, a1 = 0.f, a2 = 0.f, a3 = 0.f;
#pragma unroll
                    for (int bb = 0; bb < 64; bb += 4) {
                        a0 = fmaf(sS[(base + bb + 0) * SSTR + i], sS[(base + bb + 0) * SSTR + j], a0);
                        a1 = fmaf(sS[(base + bb + 1) * SSTR + i], sS[(base + bb + 1) * SSTR + j], a1);
                        a2 = fmaf(sS[(base + bb + 2) * SSTR + i], sS[(base + bb + 2) * SSTR + j], a2);
                        a3 = fmaf(sS[(base + bb + 3) * SSTR + i], sS[(base + bb + 3) * SSTR + j], a3);
                    }
                    sCoQ[q][t] = (a0 + a1) + (a2 + a3);
                }
            }
            __syncthreads();

            // ---- store this block's private slot (LLC-direct, no RMW) ----
            if (tid < 225) {
                float v = (sCoQ[0][tid] + sCoQ[1][tid])
                        + (sCoQ[2][tid] + sCoQ[3][tid]);
                __hip_atomic_store(
                    &coact[((size_t)s * MAXBLK + blockIdx.x) * CSTRIDE + tid], v,
                    __ATOMIC_RELAXED, __HIP_MEMORY_SCOPE_AGENT);
            }
            __syncthreads();   // drains vmcnt: slot stores complete at LLC

            // ---- flag-based barrier: store own flag, wave0 polls all ----
            if (tid == 0)
                __hip_atomic_store(&bar[s * MAXBLK + blockIdx.x], 1u,
                                   __ATOMIC_RELAXED, __HIP_MEMORY_SCOPE_AGENT);
            if (tid < 64) {
                const unsigned* bs = bar + s * MAXBLK;
                for (;;) {
                    unsigned f = 1u;
#pragma unroll
                    for (int k = 0; k < 4; ++k) {
                        int b = tid + k * 64;
                        unsigned v = (b < nblk)
                            ? __hip_atomic_load(&bs[b], __ATOMIC_RELAXED,
                                                __HIP_MEMORY_SCOPE_AGENT)
                            : 1u;
                        f &= v;
                    }
                    if (__all(f != 0)) break;
                    __builtin_amdgcn_s_sleep(1);
                }
            }
            __syncthreads();
        }
    }
}

extern "C" void kernel_launch(void* const* d_in, const int* in_sizes, int n_in,
                              void* d_out, int out_size, void* d_ws, size_t ws_size,
                              hipStream_t stream) {
    (void)n_in; (void)out_size; (void)ws_size;
    const float* x     = (const float*)d_in[0];
    const float* Wi    = (const float*)d_in[1];
    const float* bi    = (const float*)d_in[2];
    const float* gamma = (const float*)d_in[3];
    const float* beta  = (const float*)d_in[4];
    const float* R     = (const float*)d_in[5];
    const float* rb    = (const float*)d_in[6];
    const float* mask  = (const float*)d_in[7];
    const float* Wc    = (const float*)d_in[8];
    const float* bc    = (const float*)d_in[9];
    const float* Wo    = (const float*)d_in[10];
    const float* bo    = (const float*)d_in[11];
    float* out = (float*)d_out;

    const int B = in_sizes[0] / (IMSZ * IMSZ);
    const float invB = 1.0f / (float)B;
    int grid = B / 256;                      // 256 samples per block -> 256 blocks

    // workspace: flags 4*256 u32 | coact 4 steps * 256 slots * CSTRIDE f32
    unsigned* bar = (unsigned*)d_ws;
    float* coact = (float*)((char*)d_ws + 4 * MAXBLK * sizeof(unsigned));

    // only flags need zeroing (coact slots are fully overwritten before read)
    hipMemsetAsync(d_ws, 0, (size_t)4 * MAXBLK * sizeof(unsigned), stream);

    fused5<<<grid, 1024, 0, stream>>>(
        x, Wi, bi, gamma, beta, R, rb, mask, Wc, bc, Wo, bo,
        coact, bar, out, invB, grid);
}